// Round 6
// baseline (25.115 us; speedup 1.0000x reference)
//
#include <hip/hip_runtime.h>

// B=64, T=14, 4 Bayer planes (RGGB), H=W=96. Only t=0 used.
// Fused: demosaic -> [64,3,192,192] -> bilinear 2x -> [64,3,384,384] f32.
constexpr int Hh = 96, Wh = 96;
constexpr int PLANE = Hh * Wh;          // 9216
constexpr int BSTRIDE = 14 * 4 * PLANE; // batch stride (T=14)
constexpr int ON = 384;                 // output dim
constexpr int QN = 96;                  // col-quads per row
constexpr int KTN = 48;                 // k-tiles (4 demosaic rows each)
constexpr int BLK_PER_IMG = KTN * QN / 256;  // 18 blocks per (b,ch)

typedef float f32x4 __attribute__((ext_vector_type(4)));

__device__ __forceinline__ float rcpn(float n) {
  // n in {2,3,4}
  return (n == 2.0f) ? 0.5f : ((n == 3.0f) ? (1.0f / 3.0f) : 0.25f);
}

__device__ __forceinline__ void hblend(float D0, float D1, float D2, float D3,
                                       float* __restrict__ h) {
  h[0] = 0.25f * D0 + 0.75f * D1;
  h[1] = 0.75f * D1 + 0.25f * D2;
  h[2] = 0.25f * D1 + 0.75f * D2;
  h[3] = 0.75f * D2 + 0.25f * D3;
}

// Each thread: one channel, demosaic rows k0-1..k0+4 (k0=4*kt) -> 8 output
// rows x 4 cols. Batched dedup'd loads, branch-free compute, PLAIN float4
// stores (A/B vs round-5's nontemporal — isolating the nt flag).
__global__ __launch_bounds__(256, 6) void fused_demosaic_resize(
    const float* __restrict__ in, float* __restrict__ out) {
  const int blk = blockIdx.x;
  const int ch = blk % 3;                // wave-uniform (block-pure)
  const int rest = blk / 3;
  const int b = rest / BLK_PER_IMG;
  const int s = rest % BLK_PER_IMG;
  const int u = s * 256 + threadIdx.x;   // 0..4607 within (b,ch)
  const int kt = u / QN;
  const int q = u % QN;

  const int qm = (q > 0) ? q - 1 : 0;
  const int qp = (q < Wh - 1) ? q + 1 : Wh - 1;
  const bool qlo = (q == 0), qhi = (q == Wh - 1);

  // plane rows needed for demosaic rows 4kt-1 .. 4kt+4 (clamped)
  const int pr[4] = { (kt > 0) ? 2 * kt - 1 : 0, 2 * kt, 2 * kt + 1,
                      (kt < KTN - 1) ? 2 * kt + 2 : Hh - 1 };

  const float* base = in + (size_t)b * BSTRIDE;

  float h[6][4];  // h[i] = horizontal blends of demosaic row 4kt-1+i

  if (ch == 1) {
    // G: G1 at (even,odd), G2 at (odd,even). Cross kernel -> arm counting.
    const float* G1 = base + PLANE;
    const float* G2 = base + 2 * PLANE;
    float g1v[4][3], g2v[4][3];
#pragma unroll
    for (int i = 0; i < 4; ++i) {
      const float* a = G1 + pr[i] * Wh;
      const float* c = G2 + pr[i] * Wh;
      g1v[i][0] = a[qm]; g1v[i][1] = a[q]; g1v[i][2] = a[qp];
      g2v[i][0] = c[qm]; g2v[i][1] = c[q]; g2v[i][2] = c[qp];
    }
    const float wQm = qlo ? 0.0f : 1.0f;
    const float wQp = qhi ? 0.0f : 1.0f;
    // odd demosaic row r=2t+1: G2 native at even cols; cross at odd cols.
    auto godd = [&](const float* g1u, const float* g1d, const float* g2,
                    float wD, float* hh) {
      float D0 = (g1u[0] + g2[0] + g2[1] + wD * g1d[0]) * rcpn(3.0f + wD);
      float D1 = g2[1];
      float D2 = (g1u[1] + g2[1] + wD * g1d[1] + wQp * g2[2]) * rcpn(2.0f + wD + wQp);
      float D3 = g2[2];
      if (qlo) D0 = D1;
      if (qhi) D3 = D2;
      hblend(D0, D1, D2, D3, hh);
    };
    // even demosaic row r=2t: G1 native at odd cols; cross at even cols.
    auto geven = [&](const float* g1, const float* g2u, const float* g2d,
                     float wU, float* hh) {
      float D0 = g1[0];
      float D1 = (g1[1] + g2d[1] + wQm * g1[0] + wU * g2u[1]) * rcpn(2.0f + wQm + wU);
      float D2 = g1[1];
      float D3 = (g1[2] + g2d[2] + g1[1] + wU * g2u[2]) * rcpn(3.0f + wU);
      if (qlo) D0 = D1;
      if (qhi) D3 = D2;
      hblend(D0, D1, D2, D3, hh);
    };
    godd (g1v[0], g1v[1], g2v[0], 1.0f, h[0]);                         // d(4kt-1)
    geven(g1v[1], g2v[0], g2v[1], (kt > 0) ? 1.0f : 0.0f, h[1]);       // d(4kt)
    godd (g1v[1], g1v[2], g2v[1], 1.0f, h[2]);                         // d(4kt+1)
    geven(g1v[2], g2v[1], g2v[2], 1.0f, h[3]);                         // d(4kt+2)
    godd (g1v[2], g1v[3], g2v[2], (kt < KTN - 1) ? 1.0f : 0.0f, h[4]); // d(4kt+3)
    geven(g1v[3], g2v[2], g2v[3], 1.0f, h[5]);                         // d(4kt+4)
  } else {
    // R at (even,even) / B at (odd,odd): clamp-duplication == conv/den renorm.
    const float* P = (ch == 0) ? base : base + 3 * PLANE;
    float A[4][3];
#pragma unroll
    for (int i = 0; i < 4; ++i) {
      const float* r = P + pr[i] * Wh;
      A[i][0] = r[qm]; A[i][1] = r[q]; A[i][2] = r[qp];
    }
    if (ch == 0) {
      auto rrow = [&](float a, float b_, float c, float* hh) {
        hblend(0.5f * (a + b_), b_, 0.5f * (b_ + c), c, hh);
      };
      rrow(0.5f * (A[0][0] + A[1][0]), 0.5f * (A[0][1] + A[1][1]), 0.5f * (A[0][2] + A[1][2]), h[0]);
      rrow(A[1][0], A[1][1], A[1][2], h[1]);
      rrow(0.5f * (A[1][0] + A[2][0]), 0.5f * (A[1][1] + A[2][1]), 0.5f * (A[1][2] + A[2][2]), h[2]);
      rrow(A[2][0], A[2][1], A[2][2], h[3]);
      rrow(0.5f * (A[2][0] + A[3][0]), 0.5f * (A[2][1] + A[3][1]), 0.5f * (A[2][2] + A[3][2]), h[4]);
      rrow(A[3][0], A[3][1], A[3][2], h[5]);
    } else {
      auto brow = [&](float a, float b_, float c, float* hh) {
        hblend(a, 0.5f * (a + b_), b_, 0.5f * (b_ + c), hh);
      };
      brow(A[0][0], A[0][1], A[0][2], h[0]);
      brow(0.5f * (A[0][0] + A[1][0]), 0.5f * (A[0][1] + A[1][1]), 0.5f * (A[0][2] + A[1][2]), h[1]);
      brow(A[1][0], A[1][1], A[1][2], h[2]);
      brow(0.5f * (A[1][0] + A[2][0]), 0.5f * (A[1][1] + A[2][1]), 0.5f * (A[1][2] + A[2][2]), h[3]);
      brow(A[2][0], A[2][1], A[2][2], h[4]);
      brow(0.5f * (A[2][0] + A[3][0]), 0.5f * (A[2][1] + A[3][1]), 0.5f * (A[2][2] + A[3][2]), h[5]);
    }
  }

  // tile-edge overrides: required for G (structure flips at clamped rows);
  // value-neutral for R/B (clamped rows already duplicate).
#pragma unroll
  for (int j = 0; j < 4; ++j) {
    if (kt == 0)       h[0][j] = h[1][j];
    if (kt == KTN - 1) h[5][j] = h[4][j];
  }

  float* op = out + (size_t)(((b * 3 + ch) * ON + 8 * kt) * ON + 4 * q);
#pragma unroll
  for (int m = 0; m < 4; ++m) {
    f32x4 v;
    v.x = 0.25f * h[m][0] + 0.75f * h[m + 1][0];
    v.y = 0.25f * h[m][1] + 0.75f * h[m + 1][1];
    v.z = 0.25f * h[m][2] + 0.75f * h[m + 1][2];
    v.w = 0.25f * h[m][3] + 0.75f * h[m + 1][3];
    *reinterpret_cast<f32x4*>(op) = v;
    op += ON;
    v.x = 0.75f * h[m + 1][0] + 0.25f * h[m + 2][0];
    v.y = 0.75f * h[m + 1][1] + 0.25f * h[m + 2][1];
    v.z = 0.75f * h[m + 1][2] + 0.25f * h[m + 2][2];
    v.w = 0.75f * h[m + 1][3] + 0.25f * h[m + 2][3];
    *reinterpret_cast<f32x4*>(op) = v;
    op += ON;
  }
}

extern "C" void kernel_launch(void* const* d_in, const int* in_sizes, int n_in,
                              void* d_out, int out_size, void* d_ws, size_t ws_size,
                              hipStream_t stream) {
  const float* in = (const float*)d_in[0];
  float* out = (float*)d_out;
  const int total_blocks = 64 * 3 * BLK_PER_IMG;  // 3456 blocks
  fused_demosaic_resize<<<total_blocks, 256, 0, stream>>>(in, out);
}